// Round 13
// baseline (294.476 us; speedup 1.0000x reference)
//
#include <hip/hip_runtime.h>

#define N_NODES 100000
#define N_EDGES 1600000
#define NB_SCAN 391    // ceil(N_NODES / 256)
#define NSLICE 64      // edge slices
#define SLICE_E 25000  // N_EDGES / NSLICE
#define NBUCK 4        // node buckets
#define BUCK_N 25000   // nodes per bucket (N_NODES / NBUCK)
#define BUCK_W 12500   // uint32 words per bucket (2x uint16 packed)

__device__ __forceinline__ unsigned short f2bf(float f) {   // RNE fp32->bf16
    unsigned int u = __float_as_uint(f);
    return (unsigned short)((u + 0x7FFFu + ((u >> 16) & 1u)) >> 16);
}

// ---------------- LDS-bucketed histogram (no global atomics) ----------------

template <bool RANK>
__global__ void __launch_bounds__(512) count_kernel(
        const int* __restrict__ ids,
        unsigned short* __restrict__ slicecnt,   // [NSLICE][N_NODES] u16
        unsigned short* __restrict__ rank16) {   // [N_EDGES] u16 (RANK only)
    __shared__ unsigned int cnt[BUCK_W];
    int s = blockIdx.x >> 2;
    int b = blockIdx.x & 3;
    int b0 = b * BUCK_N;
    for (int w = threadIdx.x; w < BUCK_W; w += 512) cnt[w] = 0;
    __syncthreads();
    int base = s * SLICE_E;
    for (int i = threadIdx.x; i < SLICE_E; i += 512) {
        int e = base + i;
        int id = ids[e] - b0;
        if ((unsigned)id < (unsigned)BUCK_N) {
            unsigned int shift = (id & 1) * 16;
            unsigned int old = atomicAdd(&cnt[id >> 1], 1u << shift);
            if (RANK) rank16[e] = (unsigned short)((old >> shift) & 0xFFFFu);
        }
    }
    __syncthreads();
    unsigned int* row = (unsigned int*)(slicecnt + (size_t)s * N_NODES) + b * BUCK_W;
    for (int w = threadIdx.x; w < BUCK_W; w += 512) row[w] = cnt[w];
}

// per-node scan over slice counts: dst counts -> slice offsets (in place),
// in-degree + norms. norm_dst pre-scaled by 1/32767 (ew 15-bit dequant folded).
__global__ void scan_slices_kernel(unsigned short* __restrict__ scd,
                                   const unsigned short* __restrict__ scs,
                                   int* __restrict__ deg_int,
                                   float* __restrict__ ndq,
                                   float* __restrict__ norm_src) {
    int n = blockIdx.x * blockDim.x + threadIdx.x;
    if (n >= N_NODES) return;
    unsigned int tot = 0;
    for (int s = 0; s < NSLICE; ++s) {
        size_t idx = (size_t)s * N_NODES + n;
        unsigned int c = scd[idx];
        scd[idx] = (unsigned short)tot;
        tot += c;
    }
    deg_int[n] = (int)tot;
    ndq[n] = rsqrtf(fmaxf((float)tot, 1.0f)) * (1.0f / 32767.0f);
    unsigned int so = 0;
    for (int s = 0; s < NSLICE; ++s) so += scs[(size_t)s * N_NODES + n];
    norm_src[n] = rsqrtf(fmaxf((float)so, 1.0f));
}

// ---------------- 3-phase device-wide exclusive scan of in-degrees ----------------

__global__ void block_sum_kernel(const int* __restrict__ deg_in, int* __restrict__ block_sums) {
    __shared__ int sdata[256];
    int t = threadIdx.x;
    int n = blockIdx.x * 256 + t;
    int v = (n < N_NODES) ? deg_in[n] : 0;
    sdata[t] = v;
    __syncthreads();
    for (int off = 128; off > 0; off >>= 1) {
        if (t < off) sdata[t] += sdata[t + off];
        __syncthreads();
    }
    if (t == 0) block_sums[blockIdx.x] = sdata[0];
}

__global__ void scan_blocks_kernel(const int* __restrict__ block_sums, int* __restrict__ block_off) {
    __shared__ int part[512];
    int t = threadIdx.x;
    int v = (t < NB_SCAN) ? block_sums[t] : 0;
    part[t] = v;
    __syncthreads();
    for (int off = 1; off < 512; off <<= 1) {
        int u = (t >= off) ? part[t - off] : 0;
        __syncthreads();
        part[t] += u;
        __syncthreads();
    }
    if (t < NB_SCAN) block_off[t] = part[t] - v;   // exclusive
}

__global__ void scatter_rowptr_kernel(const int* __restrict__ deg_in,
                                      const int* __restrict__ block_off,
                                      int* __restrict__ row_ptr) {
    __shared__ int part[256];
    int t = threadIdx.x;
    int n = blockIdx.x * 256 + t;
    int v = (n < N_NODES) ? deg_in[n] : 0;
    part[t] = v;
    __syncthreads();
    for (int off = 1; off < 256; off <<= 1) {
        int u = (t >= off) ? part[t - off] : 0;
        __syncthreads();
        part[t] += u;
        __syncthreads();
    }
    int excl = part[t] - v + block_off[blockIdx.x];
    if (n < N_NODES) row_ptr[n] = excl;
    if (n == N_NODES - 1) row_ptr[N_NODES] = excl + v;
}

// ---------------- atomic-free CSR fill (4B packed records) ----------------
// slot = row_ptr[d] + sliceoff[slice][d] + rank  ;  rec = (src<<15) | ew15

__global__ void fill_kernel(const int* __restrict__ src, const int* __restrict__ dst,
                            const float* __restrict__ ew,
                            const int* __restrict__ row_ptr,
                            const unsigned short* __restrict__ sliceoff,
                            const unsigned short* __restrict__ rank16,
                            unsigned int* __restrict__ epack) {
    int i = blockIdx.x * blockDim.x + threadIdx.x;
    int stride = gridDim.x * blockDim.x;
    for (int e = i; e < N_EDGES; e += stride) {
        int s = src[e], d = dst[e];
        int sl = e / SLICE_E;
        int slot = row_ptr[d] + (int)sliceoff[(size_t)sl * N_NODES + d] + (int)rank16[e];
        unsigned int q = (unsigned int)(ew[e] * 32767.0f + 0.5f);
        epack[slot] = ((unsigned int)s << 15) | q;
    }
}

// ---------------- dense transform: h = ns ⊙ (act(x [+b]) @ W) -> bf16 ----------------

template <int BM, int DOUT, bool BIAS_RELU>
__global__ void __launch_bounds__(256) matmul_kernel(
        const float* __restrict__ x, const float* __restrict__ W,
        const float* __restrict__ bin, const float* __restrict__ ns,
        unsigned short* __restrict__ h) {
    constexpr int S = 65;
    constexpr int CG = DOUT / 4;
    __shared__ float Xs[BM * S];
    __shared__ float Ws[64 * DOUT];
    int tid = threadIdx.x;
    int n0 = blockIdx.x * BM;

    for (int i = tid; i < 16 * DOUT; i += 256)
        ((float4*)Ws)[i] = ((const float4*)W)[i];

    float4 bv4;
    if (BIAS_RELU) bv4 = ((const float4*)bin)[tid & 15];
    int c0 = (tid & 15) * 4;
    for (int r = tid >> 4; r < BM; r += 16) {
        int n = n0 + r;
        int nc = n < N_NODES ? n : N_NODES - 1;
        float4 v = ((const float4*)(x + (size_t)nc * 64))[tid & 15];
        if (BIAS_RELU) {
            v.x = fmaxf(v.x + bv4.x, 0.0f);
            v.y = fmaxf(v.y + bv4.y, 0.0f);
            v.z = fmaxf(v.z + bv4.z, 0.0f);
            v.w = fmaxf(v.w + bv4.w, 0.0f);
        }
        Xs[r * S + c0]     = v.x;
        Xs[r * S + c0 + 1] = v.y;
        Xs[r * S + c0 + 2] = v.z;
        Xs[r * S + c0 + 3] = v.w;
    }
    __syncthreads();

    int cg = tid % CG;
    int ng = tid / CG;
    float acc[4][4];
#pragma unroll
    for (int i = 0; i < 4; ++i)
#pragma unroll
        for (int j = 0; j < 4; ++j) acc[i][j] = 0.0f;

#pragma unroll 16
    for (int k = 0; k < 64; ++k) {
        float4 wk = *(const float4*)(&Ws[k * DOUT + cg * 4]);
        float xk[4];
#pragma unroll
        for (int i = 0; i < 4; ++i) xk[i] = Xs[(ng * 4 + i) * S + k];
#pragma unroll
        for (int i = 0; i < 4; ++i) {
            acc[i][0] = fmaf(xk[i], wk.x, acc[i][0]);
            acc[i][1] = fmaf(xk[i], wk.y, acc[i][1]);
            acc[i][2] = fmaf(xk[i], wk.z, acc[i][2]);
            acc[i][3] = fmaf(xk[i], wk.w, acc[i][3]);
        }
    }

#pragma unroll
    for (int i = 0; i < 4; ++i) {
        int n = n0 + ng * 4 + i;
        if (n < N_NODES) {
            float nsv = ns[n];
            ushort4 o;
            o.x = f2bf(acc[i][0] * nsv); o.y = f2bf(acc[i][1] * nsv);
            o.z = f2bf(acc[i][2] * nsv); o.w = f2bf(acc[i][3] * nsv);
            *(ushort4*)(&h[(size_t)n * DOUT + cg * 4]) = o;
        }
    }
}

// ---------------- CSR aggregation: paired-edge u32 gather ----------------
// Wave per node. h row = G = D/2 u32 words; wave splits into EPL = 64/G lane
// groups, each group fetching a DIFFERENT edge's row -> one 256B VMEM covers
// 2 (D=64) or 4 (D=32) edges, halving gather instrs + latency batches (R12:
// deg~16 needed 2+ serial 8-deep waits). Cross-group combine via shfl(^32).

template <int D, bool FINAL>
__global__ void __launch_bounds__(256) csr_agg_kernel(
        const int* __restrict__ row_ptr,
        const unsigned int* __restrict__ epack,
        const unsigned short* __restrict__ h,
        const float* __restrict__ ndq,
        const float* __restrict__ bias, float* __restrict__ out) {
    constexpr int G = D / 2;          // u32 words per h row
    constexpr int EPL = 64 / G;       // edges in flight per step (2 or 4)
    int tid = blockIdx.x * blockDim.x + threadIdx.x;
    int wave = tid >> 6;
    int nwaves = (gridDim.x * blockDim.x) >> 6;
    int lane = threadIdx.x & 63;
    int grp = lane / G;
    int j = lane % G;
    const unsigned int* hw = (const unsigned int*)h;   // row stride G words

    float bx = 0.f, by = 0.f;
    if (FINAL) { bx = bias[2 * j]; by = bias[2 * j + 1]; }

    for (int n = wave; n < N_NODES; n += nwaves) {
        int s = row_ptr[n];
        int e = row_ptr[n + 1];
        float ax0 = 0.f, ay0 = 0.f, ax1 = 0.f, ay1 = 0.f;
        float ax2 = 0.f, ay2 = 0.f, ax3 = 0.f, ay3 = 0.f;
        int i = s;
        for (; i + 4 * EPL <= e; i += 4 * EPL) {
            unsigned int p0 = epack[i + grp];
            unsigned int p1 = epack[i + EPL + grp];
            unsigned int p2 = epack[i + 2 * EPL + grp];
            unsigned int p3 = epack[i + 3 * EPL + grp];
            unsigned int h0 = hw[(size_t)(p0 >> 15) * G + j];
            unsigned int h1 = hw[(size_t)(p1 >> 15) * G + j];
            unsigned int h2 = hw[(size_t)(p2 >> 15) * G + j];
            unsigned int h3 = hw[(size_t)(p3 >> 15) * G + j];
            float c0 = (float)(p0 & 32767u);
            float c1 = (float)(p1 & 32767u);
            float c2 = (float)(p2 & 32767u);
            float c3 = (float)(p3 & 32767u);
            ax0 = fmaf(__uint_as_float(h0 << 16), c0, ax0);
            ay0 = fmaf(__uint_as_float(h0 & 0xFFFF0000u), c0, ay0);
            ax1 = fmaf(__uint_as_float(h1 << 16), c1, ax1);
            ay1 = fmaf(__uint_as_float(h1 & 0xFFFF0000u), c1, ay1);
            ax2 = fmaf(__uint_as_float(h2 << 16), c2, ax2);
            ay2 = fmaf(__uint_as_float(h2 & 0xFFFF0000u), c2, ay2);
            ax3 = fmaf(__uint_as_float(h3 << 16), c3, ax3);
            ay3 = fmaf(__uint_as_float(h3 & 0xFFFF0000u), c3, ay3);
        }
        for (; i < e; i += EPL) {
            int idx = i + grp;
            bool valid = idx < e;
            unsigned int p = epack[valid ? idx : s];
            unsigned int hv = hw[(size_t)(p >> 15) * G + j];
            float c = valid ? (float)(p & 32767u) : 0.0f;
            ax0 = fmaf(__uint_as_float(hv << 16), c, ax0);
            ay0 = fmaf(__uint_as_float(hv & 0xFFFF0000u), c, ay0);
        }
        float sx = (ax0 + ax1) + (ax2 + ax3);
        float sy = (ay0 + ay1) + (ay2 + ay3);
        if (EPL == 4) {
            sx += __shfl(sx, lane ^ 16);
            sy += __shfl(sy, lane ^ 16);
        }
        sx += __shfl(sx, lane ^ 32);
        sy += __shfl(sy, lane ^ 32);
        if (grp == 0) {
            float nv = ndq[n];
            float2 o;
            o.x = fmaf(sx, nv, bx);
            o.y = fmaf(sy, nv, by);
            *(float2*)(&out[(size_t)n * D + 2 * j]) = o;
        }
    }
}

extern "C" void kernel_launch(void* const* d_in, const int* in_sizes, int n_in,
                              void* d_out, int out_size, void* d_ws, size_t ws_size,
                              hipStream_t stream) {
    const float* features = (const float*)d_in[0];
    const float* ew       = (const float*)d_in[1];
    const int*   src      = (const int*)d_in[2];
    const int*   dst      = (const int*)d_in[3];
    const float* W1       = (const float*)d_in[4];
    const float* b1       = (const float*)d_in[5];
    const float* W2       = (const float*)d_in[6];
    const float* b2       = (const float*)d_in[7];
    const float* Wp       = (const float*)d_in[8];
    const float* bp       = (const float*)d_in[9];
    float* out = (float*)d_out;

    // workspace layout (explicit 4B-unit offsets)
    float* ws = (float*)d_ws;
    float* norm_src = ws;                             // @0        N
    float* ndq      = ws + 100000;                    // @100000   N  (nd / 32767)
    int*   deg_int  = (int*)(ws + 200000);            // @200000   N
    int*   row_ptr  = (int*)(ws + 300000);            // @300000   N+1
    int*   block_sums = (int*)(ws + 400002);          // @400002   NB_SCAN
    int*   block_off  = (int*)(ws + 400394);          // @400394   NB_SCAN
    unsigned short* rank16 = (unsigned short*)(ws + 400800);  // 1.6M u16
    unsigned int*   epack  = (unsigned int*)(ws + 1200800);   // E u32
    unsigned short* hbuf   = (unsigned short*)(ws + 2800800); // N*64 bf16 (3.2M f)
    float*          bufA   = ws + 6000800;                    // N*64 fp32 (6.4M f)

    // slice-count buffers alias hbuf/bufA (dead once fill completes)
    unsigned short* slicecnt_dst = hbuf;                    // becomes sliceoff
    unsigned short* slicecnt_src = (unsigned short*)bufA;

    // ---- CSR + norms build: zero global atomics ----
    count_kernel<true><<<NSLICE * NBUCK, 512, 0, stream>>>(dst, slicecnt_dst, rank16);
    count_kernel<false><<<NSLICE * NBUCK, 512, 0, stream>>>(src, slicecnt_src, nullptr);
    scan_slices_kernel<<<NB_SCAN, 256, 0, stream>>>(slicecnt_dst, slicecnt_src,
                                                    deg_int, ndq, norm_src);
    block_sum_kernel<<<NB_SCAN, 256, 0, stream>>>(deg_int, block_sums);
    scan_blocks_kernel<<<1, 512, 0, stream>>>(block_sums, block_off);
    scatter_rowptr_kernel<<<NB_SCAN, 256, 0, stream>>>(deg_int, block_off, row_ptr);
    fill_kernel<<<2048, 256, 0, stream>>>(src, dst, ew, row_ptr,
                                          slicecnt_dst, rank16, epack);

    // ---- layer 1: h1 = ns ⊙ (features @ W1) ; bufA = ndq ⊙ Σ ew·h1
    matmul_kernel<64, 64, false><<<1563, 256, 0, stream>>>(features, W1, nullptr, norm_src, hbuf);
    csr_agg_kernel<64, false><<<4096, 256, 0, stream>>>(row_ptr, epack, hbuf, ndq, nullptr, bufA);

    // ---- layer 2: h2 = ns ⊙ (relu(bufA + b1) @ W2) ; bufA = ndq ⊙ Σ ew·h2
    matmul_kernel<64, 64, true><<<1563, 256, 0, stream>>>(bufA, W2, b1, norm_src, hbuf);
    csr_agg_kernel<64, false><<<4096, 256, 0, stream>>>(row_ptr, epack, hbuf, ndq, nullptr, bufA);

    // ---- layer 3: h3 = ns ⊙ (relu(bufA + b2) @ Wp) ; out = ndq ⊙ Σ ew·h3 + bp
    matmul_kernel<128, 32, true><<<782, 256, 0, stream>>>(bufA, Wp, b2, norm_src, hbuf);
    csr_agg_kernel<32, true><<<4096, 256, 0, stream>>>(row_ptr, epack, hbuf, ndq, bp, out);
}

// Round 14
// 257.780 us; speedup vs baseline: 1.1424x; 1.1424x over previous
//
#include <hip/hip_runtime.h>

#define N_NODES 100000
#define N_EDGES 1600000
#define NB_SCAN 391    // ceil(N_NODES / 256)
#define NSLICE 64      // edge slices
#define SLICE_E 25000  // N_EDGES / NSLICE
#define NBUCK 4        // node buckets
#define BUCK_N 25000   // nodes per bucket (N_NODES / NBUCK)
#define BUCK_W 12500   // uint32 words per bucket (2x uint16 packed)

__device__ __forceinline__ unsigned short f2bf(float f) {   // RNE fp32->bf16
    unsigned int u = __float_as_uint(f);
    return (unsigned short)((u + 0x7FFFu + ((u >> 16) & 1u)) >> 16);
}

// ---------------- LDS-bucketed histogram (no global atomics) ----------------

template <bool RANK>
__global__ void __launch_bounds__(512) count_kernel(
        const int* __restrict__ ids,
        unsigned short* __restrict__ slicecnt,   // [NSLICE][N_NODES] u16
        unsigned short* __restrict__ rank16) {   // [N_EDGES] u16 (RANK only)
    __shared__ unsigned int cnt[BUCK_W];
    int s = blockIdx.x >> 2;
    int b = blockIdx.x & 3;
    int b0 = b * BUCK_N;
    for (int w = threadIdx.x; w < BUCK_W; w += 512) cnt[w] = 0;
    __syncthreads();
    int base = s * SLICE_E;
    for (int i = threadIdx.x; i < SLICE_E; i += 512) {
        int e = base + i;
        int id = ids[e] - b0;
        if ((unsigned)id < (unsigned)BUCK_N) {
            unsigned int shift = (id & 1) * 16;
            unsigned int old = atomicAdd(&cnt[id >> 1], 1u << shift);
            if (RANK) rank16[e] = (unsigned short)((old >> shift) & 0xFFFFu);
        }
    }
    __syncthreads();
    unsigned int* row = (unsigned int*)(slicecnt + (size_t)s * N_NODES) + b * BUCK_W;
    for (int w = threadIdx.x; w < BUCK_W; w += 512) row[w] = cnt[w];
}

// per-node scan over slice counts (dst -> slice offsets in place), in-degree,
// norms (nd pre-scaled by 1/32767), PLUS fused per-block degree sums.
__global__ void scan_slices_kernel(unsigned short* __restrict__ scd,
                                   const unsigned short* __restrict__ scs,
                                   int* __restrict__ deg_int,
                                   float* __restrict__ ndq,
                                   float* __restrict__ norm_src,
                                   int* __restrict__ block_sums) {
    __shared__ int sdata[256];
    int t = threadIdx.x;
    int n = blockIdx.x * blockDim.x + t;
    int deg = 0;
    if (n < N_NODES) {
        unsigned int tot = 0;
        for (int s = 0; s < NSLICE; ++s) {
            size_t idx = (size_t)s * N_NODES + n;
            unsigned int c = scd[idx];
            scd[idx] = (unsigned short)tot;
            tot += c;
        }
        deg = (int)tot;
        deg_int[n] = deg;
        ndq[n] = rsqrtf(fmaxf((float)tot, 1.0f)) * (1.0f / 32767.0f);
        unsigned int so = 0;
        for (int s = 0; s < NSLICE; ++s) so += scs[(size_t)s * N_NODES + n];
        norm_src[n] = rsqrtf(fmaxf((float)so, 1.0f));
    }
    sdata[t] = deg;
    __syncthreads();
    for (int off = 128; off > 0; off >>= 1) {
        if (t < off) sdata[t] += sdata[t + off];
        __syncthreads();
    }
    if (t == 0) block_sums[blockIdx.x] = sdata[0];
}

// ---------------- device-wide exclusive scan (block level) ----------------

__global__ void scan_blocks_kernel(const int* __restrict__ block_sums, int* __restrict__ block_off) {
    __shared__ int part[512];
    int t = threadIdx.x;
    int v = (t < NB_SCAN) ? block_sums[t] : 0;
    part[t] = v;
    __syncthreads();
    for (int off = 1; off < 512; off <<= 1) {
        int u = (t >= off) ? part[t - off] : 0;
        __syncthreads();
        part[t] += u;
        __syncthreads();
    }
    if (t < NB_SCAN) block_off[t] = part[t] - v;   // exclusive
}

__global__ void scatter_rowptr_kernel(const int* __restrict__ deg_in,
                                      const int* __restrict__ block_off,
                                      int* __restrict__ row_ptr) {
    __shared__ int part[256];
    int t = threadIdx.x;
    int n = blockIdx.x * 256 + t;
    int v = (n < N_NODES) ? deg_in[n] : 0;
    part[t] = v;
    __syncthreads();
    for (int off = 1; off < 256; off <<= 1) {
        int u = (t >= off) ? part[t - off] : 0;
        __syncthreads();
        part[t] += u;
        __syncthreads();
    }
    int excl = part[t] - v + block_off[blockIdx.x];
    if (n < N_NODES) row_ptr[n] = excl;
    if (n == N_NODES - 1) row_ptr[N_NODES] = excl + v;
}

// ---------------- atomic-free CSR fill (4B packed records) ----------------
// slot = row_ptr[d] + sliceoff[slice][d] + rank  ;  rec = (src<<15) | ew15

__global__ void fill_kernel(const int* __restrict__ src, const int* __restrict__ dst,
                            const float* __restrict__ ew,
                            const int* __restrict__ row_ptr,
                            const unsigned short* __restrict__ sliceoff,
                            const unsigned short* __restrict__ rank16,
                            unsigned int* __restrict__ epack) {
    int i = blockIdx.x * blockDim.x + threadIdx.x;
    int stride = gridDim.x * blockDim.x;
    for (int e = i; e < N_EDGES; e += stride) {
        int s = src[e], d = dst[e];
        int sl = e / SLICE_E;
        int slot = row_ptr[d] + (int)sliceoff[(size_t)sl * N_NODES + d] + (int)rank16[e];
        unsigned int q = (unsigned int)(ew[e] * 32767.0f + 0.5f);
        epack[slot] = ((unsigned int)s << 15) | q;
    }
}

// ---------------- dense transform: h = ns ⊙ (act(x [+b]) @ W) -> bf16 ----------------

template <int BM, int DOUT, bool BIAS_RELU>
__global__ void __launch_bounds__(256) matmul_kernel(
        const float* __restrict__ x, const float* __restrict__ W,
        const float* __restrict__ bin, const float* __restrict__ ns,
        unsigned short* __restrict__ h) {
    constexpr int S = 65;
    constexpr int CG = DOUT / 4;
    __shared__ float Xs[BM * S];
    __shared__ float Ws[64 * DOUT];
    int tid = threadIdx.x;
    int n0 = blockIdx.x * BM;

    for (int i = tid; i < 16 * DOUT; i += 256)
        ((float4*)Ws)[i] = ((const float4*)W)[i];

    float4 bv4;
    if (BIAS_RELU) bv4 = ((const float4*)bin)[tid & 15];
    int c0 = (tid & 15) * 4;
    for (int r = tid >> 4; r < BM; r += 16) {
        int n = n0 + r;
        int nc = n < N_NODES ? n : N_NODES - 1;
        float4 v = ((const float4*)(x + (size_t)nc * 64))[tid & 15];
        if (BIAS_RELU) {
            v.x = fmaxf(v.x + bv4.x, 0.0f);
            v.y = fmaxf(v.y + bv4.y, 0.0f);
            v.z = fmaxf(v.z + bv4.z, 0.0f);
            v.w = fmaxf(v.w + bv4.w, 0.0f);
        }
        Xs[r * S + c0]     = v.x;
        Xs[r * S + c0 + 1] = v.y;
        Xs[r * S + c0 + 2] = v.z;
        Xs[r * S + c0 + 3] = v.w;
    }
    __syncthreads();

    int cg = tid % CG;
    int ng = tid / CG;
    float acc[4][4];
#pragma unroll
    for (int i = 0; i < 4; ++i)
#pragma unroll
        for (int j = 0; j < 4; ++j) acc[i][j] = 0.0f;

#pragma unroll 16
    for (int k = 0; k < 64; ++k) {
        float4 wk = *(const float4*)(&Ws[k * DOUT + cg * 4]);
        float xk[4];
#pragma unroll
        for (int i = 0; i < 4; ++i) xk[i] = Xs[(ng * 4 + i) * S + k];
#pragma unroll
        for (int i = 0; i < 4; ++i) {
            acc[i][0] = fmaf(xk[i], wk.x, acc[i][0]);
            acc[i][1] = fmaf(xk[i], wk.y, acc[i][1]);
            acc[i][2] = fmaf(xk[i], wk.z, acc[i][2]);
            acc[i][3] = fmaf(xk[i], wk.w, acc[i][3]);
        }
    }

#pragma unroll
    for (int i = 0; i < 4; ++i) {
        int n = n0 + ng * 4 + i;
        if (n < N_NODES) {
            float nsv = ns[n];
            ushort4 o;
            o.x = f2bf(acc[i][0] * nsv); o.y = f2bf(acc[i][1] * nsv);
            o.z = f2bf(acc[i][2] * nsv); o.w = f2bf(acc[i][3] * nsv);
            *(ushort4*)(&h[(size_t)n * DOUT + cg * 4]) = o;
        }
    }
}

// ---------------- CSR aggregation: one-shot epack row + shfl distribute ----------------
// Wave per node. Per 16-edge chunk: ONE 64B VMEM loads all records into lanes
// 0-15; __shfl hands record (i+grp) to each lane group -> all 8 (D=64) gather
// addresses ready at once (R13's chain was epack-load->gather x2 batches).
// Tail pads with p=0 (coef 0, gathers hit hot h row 0).

template <int D, bool FINAL>
__global__ void __launch_bounds__(256) csr_agg_kernel(
        const int* __restrict__ row_ptr,
        const unsigned int* __restrict__ epack,
        const unsigned short* __restrict__ h,
        const float* __restrict__ ndq,
        const float* __restrict__ bias, float* __restrict__ out) {
    constexpr int G = D / 2;          // u32 words per h row (32 or 16)
    constexpr int EPL = 64 / G;       // edges per step (2 or 4)
    int tid = blockIdx.x * blockDim.x + threadIdx.x;
    int wave = tid >> 6;
    int nwaves = (gridDim.x * blockDim.x) >> 6;
    int lane = threadIdx.x & 63;
    int grp = lane / G;
    int j = lane % G;
    int l16 = lane & 15;
    const unsigned int* hw = (const unsigned int*)h;   // row stride G words

    float bx = 0.f, by = 0.f;
    if (FINAL) { bx = bias[2 * j]; by = bias[2 * j + 1]; }

    for (int n = wave; n < N_NODES; n += nwaves) {
        int s = row_ptr[n];
        int e = row_ptr[n + 1];
        float ax[4] = {0.f, 0.f, 0.f, 0.f};
        float ay[4] = {0.f, 0.f, 0.f, 0.f};
        for (int base = s; base < e; base += 16) {
            int idx = base + l16;
            unsigned int pk = (idx < e) ? epack[idx] : 0u;
#pragma unroll
            for (int i = 0; i < 16; i += EPL) {
                constexpr int KM = 4 - 1;
                int k = i / EPL;
                unsigned int p = __shfl(pk, i + grp);
                unsigned int hv = hw[(size_t)(p >> 15) * G + j];
                float c = (float)(p & 32767u);
                ax[k & KM] = fmaf(__uint_as_float(hv << 16), c, ax[k & KM]);
                ay[k & KM] = fmaf(__uint_as_float(hv & 0xFFFF0000u), c, ay[k & KM]);
            }
        }
        float sx = (ax[0] + ax[1]) + (ax[2] + ax[3]);
        float sy = (ay[0] + ay[1]) + (ay[2] + ay[3]);
        if (EPL == 4) {
            sx += __shfl(sx, lane ^ 16);
            sy += __shfl(sy, lane ^ 16);
        }
        sx += __shfl(sx, lane ^ 32);
        sy += __shfl(sy, lane ^ 32);
        if (grp == 0) {
            float nv = ndq[n];
            float2 o;
            o.x = fmaf(sx, nv, bx);
            o.y = fmaf(sy, nv, by);
            *(float2*)(&out[(size_t)n * D + 2 * j]) = o;
        }
    }
}

extern "C" void kernel_launch(void* const* d_in, const int* in_sizes, int n_in,
                              void* d_out, int out_size, void* d_ws, size_t ws_size,
                              hipStream_t stream) {
    const float* features = (const float*)d_in[0];
    const float* ew       = (const float*)d_in[1];
    const int*   src      = (const int*)d_in[2];
    const int*   dst      = (const int*)d_in[3];
    const float* W1       = (const float*)d_in[4];
    const float* b1       = (const float*)d_in[5];
    const float* W2       = (const float*)d_in[6];
    const float* b2       = (const float*)d_in[7];
    const float* Wp       = (const float*)d_in[8];
    const float* bp       = (const float*)d_in[9];
    float* out = (float*)d_out;

    // workspace layout (explicit 4B-unit offsets)
    float* ws = (float*)d_ws;
    float* norm_src = ws;                             // @0        N
    float* ndq      = ws + 100000;                    // @100000   N  (nd / 32767)
    int*   deg_int  = (int*)(ws + 200000);            // @200000   N
    int*   row_ptr  = (int*)(ws + 300000);            // @300000   N+1
    int*   block_sums = (int*)(ws + 400002);          // @400002   NB_SCAN
    int*   block_off  = (int*)(ws + 400394);          // @400394   NB_SCAN
    unsigned short* rank16 = (unsigned short*)(ws + 400800);  // 1.6M u16
    unsigned int*   epack  = (unsigned int*)(ws + 1200800);   // E u32
    unsigned short* hbuf   = (unsigned short*)(ws + 2800800); // N*64 bf16 (3.2M f)
    float*          bufA   = ws + 6000800;                    // N*64 fp32 (6.4M f)

    // slice-count buffers alias hbuf/bufA (dead once fill completes)
    unsigned short* slicecnt_dst = hbuf;                    // becomes sliceoff
    unsigned short* slicecnt_src = (unsigned short*)bufA;

    // ---- CSR + norms build: zero global atomics ----
    count_kernel<true><<<NSLICE * NBUCK, 512, 0, stream>>>(dst, slicecnt_dst, rank16);
    count_kernel<false><<<NSLICE * NBUCK, 512, 0, stream>>>(src, slicecnt_src, nullptr);
    scan_slices_kernel<<<NB_SCAN, 256, 0, stream>>>(slicecnt_dst, slicecnt_src,
                                                    deg_int, ndq, norm_src, block_sums);
    scan_blocks_kernel<<<1, 512, 0, stream>>>(block_sums, block_off);
    scatter_rowptr_kernel<<<NB_SCAN, 256, 0, stream>>>(deg_int, block_off, row_ptr);
    fill_kernel<<<2048, 256, 0, stream>>>(src, dst, ew, row_ptr,
                                          slicecnt_dst, rank16, epack);

    // ---- layer 1: h1 = ns ⊙ (features @ W1) ; bufA = ndq ⊙ Σ ew·h1
    matmul_kernel<64, 64, false><<<1563, 256, 0, stream>>>(features, W1, nullptr, norm_src, hbuf);
    csr_agg_kernel<64, false><<<8192, 256, 0, stream>>>(row_ptr, epack, hbuf, ndq, nullptr, bufA);

    // ---- layer 2: h2 = ns ⊙ (relu(bufA + b1) @ W2) ; bufA = ndq ⊙ Σ ew·h2
    matmul_kernel<64, 64, true><<<1563, 256, 0, stream>>>(bufA, W2, b1, norm_src, hbuf);
    csr_agg_kernel<64, false><<<8192, 256, 0, stream>>>(row_ptr, epack, hbuf, ndq, nullptr, bufA);

    // ---- layer 3: h3 = ns ⊙ (relu(bufA + b2) @ Wp) ; out = ndq ⊙ Σ ew·h3 + bp
    matmul_kernel<128, 32, true><<<782, 256, 0, stream>>>(bufA, Wp, b2, norm_src, hbuf);
    csr_agg_kernel<32, true><<<8192, 256, 0, stream>>>(row_ptr, epack, hbuf, ndq, bp, out);
}